// Round 9
// baseline (2286.306 us; speedup 1.0000x reference)
//
#include <hip/hip_runtime.h>
#include <hip/hip_bf16.h>

#define EMB 64
#define XCOLS 20
#define NSYMP 15
#define BSH 7
#define BSZ 128          // nodes per bucket (1<<BSH)
#define MAXNB 1024       // supports N <= 131072
#define PCHUNK 4096
#define GT 512           // gemm block threads

__global__ void zero_kernel(int* __restrict__ p, int n) {
    int i = blockIdx.x * blockDim.x + threadIdx.x;
    if (i < n) p[i] = 0;
}

// ---------------- embedding ----------------
__global__ void embed_kernel(const int* __restrict__ x,
                             const float* __restrict__ bt,
                             const float* __restrict__ gt,
                             const float* __restrict__ st,
                             float* __restrict__ h0, int N) {
    __shared__ int xs[4 * XCOLS];
    int node = blockIdx.x * 4 + (threadIdx.x >> 6);
    int d = threadIdx.x & 63;
    if (threadIdx.x < 4 * XCOLS) {
        int n2 = blockIdx.x * 4 + threadIdx.x / XCOLS;
        int c = threadIdx.x % XCOLS;
        xs[threadIdx.x] = (n2 < N) ? x[n2 * XCOLS + c] : 0;
    }
    __syncthreads();
    if (node >= N) return;
    const int* xr = &xs[(threadIdx.x >> 6) * XCOLS];
    int bi = xr[1] + 2 * xr[2] + 3 * xr[3];   // argmax of one-hot
    int g = xr[4];
    float f = 0.f;
#pragma unroll
    for (int j = 0; j < NSYMP; ++j) {
        int sj = xr[5 + j];
        f += st[(j * 3 + sj) * EMB + d];
    }
    float val = (bt[bi * EMB + d] + gt[g * EMB + d] + f * (1.f / 15.f)) * (1.f / 3.f);
    h0[node * EMB + d] = val;
}

// ---------------- dual GEMM: outL = h@Wl+bl, outR = h@Wr+br (64x64 weights) ----
// Weights interleaved in LDS as wp[k/2][d][4] = (Wl[2k][d],Wr[2k][d],Wl[2k+1][d],
// Wr[2k+1][d]): one conflict-free ds_read_b128 feeds 2 k-steps of BOTH gemms.
// 2 nodes/thread, float2 broadcast h reads: 3 LDS reads per 8 FMAs.
// 512 threads, LDS=40960B -> 4 blocks/CU x 8 waves = 32 waves/CU (100% cap).
__global__ void gemm_dual_kernel(const float* __restrict__ h,
                                 const float* __restrict__ Wl, const float* __restrict__ bl,
                                 const float* __restrict__ Wr, const float* __restrict__ br,
                                 float* __restrict__ outL, float* __restrict__ outR, int N) {
    __shared__ float wp[EMB / 2][EMB][4];   // 32 KB
    __shared__ float hr[2][16][EMB];        // 8 KB (double-buffered 16-node tile)
    for (int i = threadIdx.x; i < EMB * EMB; i += GT) {
        int k = i >> 6, d = i & 63;
        wp[k >> 1][d][(k & 1) * 2 + 0] = Wl[i];
        wp[k >> 1][d][(k & 1) * 2 + 1] = Wr[i];
    }
    int w = threadIdx.x >> 6;       // wave 0..7 -> local nodes 2w, 2w+1
    int d = threadIdx.x & 63;
    int ngroups = (N + 15) / 16;
    size_t total = (size_t)N * EMB;
    float blv = bl[d], brv = br[d];
    // preload tile 0
    if (threadIdx.x < 256 && blockIdx.x < ngroups) {
        size_t idx = (size_t)blockIdx.x * 1024 + threadIdx.x * 4;
        float4 v = {0.f, 0.f, 0.f, 0.f};
        if (idx + 3 < total) v = *(const float4*)(h + idx);
        else for (int j = 0; j < 4; ++j) ((float*)&v)[j] = (idx + j < total) ? h[idx + j] : 0.f;
        ((float4*)&hr[0][0][0])[threadIdx.x] = v;
    }
    int buf = 0;
    for (int g = blockIdx.x; g < ngroups; g += gridDim.x) {
        __syncthreads();                 // hr[buf] + wp ready
        int gn = g + gridDim.x;
        if (gn < ngroups && threadIdx.x < 256) {
            size_t idx = (size_t)gn * 1024 + threadIdx.x * 4;
            float4 v = {0.f, 0.f, 0.f, 0.f};
            if (idx + 3 < total) v = *(const float4*)(h + idx);
            else for (int j = 0; j < 4; ++j) ((float*)&v)[j] = (idx + j < total) ? h[idx + j] : 0.f;
            ((float4*)&hr[buf ^ 1][0][0])[threadIdx.x] = v;
        }
        const float* h0p = &hr[buf][2 * w][0];
        const float* h1p = &hr[buf][2 * w + 1][0];
        float l0 = blv, r0 = brv, l1 = blv, r1 = brv;
#pragma unroll
        for (int kk = 0; kk < EMB / 2; ++kk) {
            float4 wv = *(const float4*)&wp[kk][d][0];
            float2 h0 = *(const float2*)(h0p + kk * 2);
            float2 h1 = *(const float2*)(h1p + kk * 2);
            l0 += h0.x * wv.x + h0.y * wv.z;
            r0 += h0.x * wv.y + h0.y * wv.w;
            l1 += h1.x * wv.x + h1.y * wv.z;
            r1 += h1.x * wv.y + h1.y * wv.w;
        }
        int node0 = g * 16 + 2 * w;
        int node1 = node0 + 1;
        if (node0 < N) { outL[node0 * EMB + d] = l0; outR[node0 * EMB + d] = r0; }
        if (node1 < N) { outL[node1 * EMB + d] = l1; outR[node1 * EMB + d] = r1; }
        buf ^= 1;
    }
}

// ---------------- CSR build via 2-level radix partition ----------------
__global__ void bincount_kernel(const int* __restrict__ ei, int* __restrict__ bcount,
                                int* __restrict__ offs, int E, int NB, int N) {
    __shared__ int lh[MAXNB];
    for (int j = threadIdx.x; j < NB; j += 256) lh[j] = 0;
    __syncthreads();
    for (int i = blockIdx.x * 256 + threadIdx.x; i < E; i += gridDim.x * 256)
        atomicAdd(&lh[ei[E + i] >> BSH], 1);
    __syncthreads();
    for (int j = threadIdx.x; j < NB; j += 256)
        if (lh[j]) atomicAdd(&bcount[j], lh[j]);
    if (blockIdx.x == 0 && threadIdx.x == 0) offs[N] = E;
}

__global__ void bscan_kernel(const int* __restrict__ bcount, int* __restrict__ boffs,
                             int* __restrict__ bcursor, int NB) {
    __shared__ int s[1024];
    int t = threadIdx.x;
    int v0 = (t < NB) ? bcount[t] : 0;
    s[t] = v0;
    __syncthreads();
    for (int off = 1; off < 1024; off <<= 1) {
        int v = (t >= off) ? s[t - off] : 0;
        __syncthreads();
        s[t] += v;
        __syncthreads();
    }
    if (t < NB) {
        boffs[t + 1] = s[t];
        bcursor[t] = s[t] - v0;
    }
    if (t == 0) boffs[0] = 0;
}

__global__ void partition_kernel(const int* __restrict__ ei, int* __restrict__ bcursor,
                                 int* __restrict__ epart, int E, int NB) {
    __shared__ int lh[MAXNB];
    for (int j = threadIdx.x; j < NB; j += 256) lh[j] = 0;
    __syncthreads();
    int base = blockIdx.x * PCHUNK;
    int end = min(E, base + PCHUNK);
    for (int i = base + threadIdx.x; i < end; i += 256)
        atomicAdd(&lh[ei[E + i] >> BSH], 1);
    __syncthreads();
    for (int j = threadIdx.x; j < NB; j += 256) {
        int c = lh[j];
        lh[j] = c ? atomicAdd(&bcursor[j], c) : 0;
    }
    __syncthreads();
    for (int i = base + threadIdx.x; i < end; i += 256) {
        int dst = ei[E + i];
        int src = ei[i];
        int slot = atomicAdd(&lh[dst >> BSH], 1);
        epart[slot] = (src << BSH) | (dst & (BSZ - 1));
    }
}

// per-wave sub-histograms/sub-cursors to cut LDS-atomic contention 4x
__global__ void finalize_kernel(const int* __restrict__ epart, const int* __restrict__ boffs,
                                int* __restrict__ offs, int* __restrict__ ssrc, int N) {
    __shared__ int deg4[4][BSZ];
    __shared__ int pos[BSZ];
    __shared__ int cur4[4][BSZ];
    int b = blockIdx.x;
    int t = threadIdx.x;
    int w = t >> 6;
    int n0 = b << BSH;
    int r0 = boffs[b], r1 = boffs[b + 1];
    ((int*)deg4)[t] = 0;
    ((int*)deg4)[t + 256] = 0;
    __syncthreads();
    for (int e = r0 + t; e < r1; e += 256)
        atomicAdd(&deg4[w][epart[e] & (BSZ - 1)], 1);
    __syncthreads();
    int d0 = 0, d1 = 0, d2 = 0, sum = 0;
    if (t < BSZ) {
        d0 = deg4[0][t]; d1 = deg4[1][t]; d2 = deg4[2][t];
        sum = d0 + d1 + d2 + deg4[3][t];
        pos[t] = sum;
    }
    __syncthreads();
    for (int off = 1; off < BSZ; off <<= 1) {
        int v = (t < BSZ && t >= off) ? pos[t - off] : 0;
        __syncthreads();
        if (t < BSZ) pos[t] += v;
        __syncthreads();
    }
    if (t < BSZ) {
        int base = r0 + pos[t] - sum;
        int node = n0 + t;
        if (node < N) offs[node] = base;
        cur4[0][t] = base;
        cur4[1][t] = base + d0;
        cur4[2][t] = base + d0 + d1;
        cur4[3][t] = base + d0 + d1 + d2;
    }
    __syncthreads();
    for (int e = r0 + t; e < r1; e += 256) {
        int v = epart[e];
        int s = atomicAdd(&cur4[w][v & (BSZ - 1)], 1);
        ssrc[s] = v >> BSH;
    }
}

// ---------------- DPP cross-lane add (VALU pipe; compiler handles hazards) --
template <int CTRL>
__device__ __forceinline__ float dpp_add(float v) {
    union { float f; int i; } u, r;
    u.f = v;
    r.i = __builtin_amdgcn_update_dpp(0, u.i, CTRL, 0xF, 0xF, true);
    return v + r.f;
}

// ---------------- GATv2 layer: 8 edges per wave iteration, pipelined --------
template <int L>
__global__ void gat_kernel(const float* __restrict__ xl, const float* __restrict__ xr,
                           const int* __restrict__ offs, const int* __restrict__ ssrc,
                           const float* __restrict__ att, const float* __restrict__ bias,
                           const float* __restrict__ linW, const float* __restrict__ linb,
                           float* __restrict__ out, int N) {
    int wid = blockIdx.x * 4 + (threadIdx.x >> 6);
    int lane = threadIdx.x & 63;
    if (wid >= N) return;
    int grp = lane >> 4;          // edge slot within the 4-wide half-batch
    int li = lane & 15;           // float4 channel slot
    unsigned cb = (unsigned)li << 2;

    const float LOG2E = 1.4426950408889634f;
    float4 att4 = *(const float4*)(att + cb);
    att4.x *= LOG2E; att4.y *= LOG2E; att4.z *= LOG2E; att4.w *= LOG2E;
    float4 bias4 = *(const float4*)(bias + cb);
    unsigned rb = (unsigned)wid << 6;
    float4 xr4 = *(const float4*)(xr + rb + cb);

    int e0 = offs[wid], e1 = offs[wid + 1];

    float s = 0.f;
    float4 acc = {0.f, 0.f, 0.f, 0.f};

    // self-loop: computed by all groups, counted by group 0 only
    {
        float4 a = *(const float4*)(xl + rb + cb);
        float ux = a.x + xr4.x; ux = fmaxf(ux, 0.2f * ux);
        float uy = a.y + xr4.y; uy = fmaxf(uy, 0.2f * uy);
        float uz = a.z + xr4.z; uz = fmaxf(uz, 0.2f * uz);
        float uw = a.w + xr4.w; uw = fmaxf(uw, 0.2f * uw);
        float part = att4.x * ux + att4.y * uy + att4.z * uz + att4.w * uw;
        part = dpp_add<0xB1>(part);
        part = dpp_add<0x4E>(part);
        if (L == 2) {
            part = dpp_add<0x141>(part);
            part = dpp_add<0x140>(part);
        }
        float p = exp2f(part);
        p = (grp == 0) ? p : 0.f;
        s += p;
        acc.x += p * a.x; acc.y += p * a.y; acc.z += p * a.z; acc.w += p * a.w;
    }

    // prologue: indices for first batch (ssrc padded -> unconditional loads OK)
    unsigned sA = (unsigned)ssrc[e0 + grp];
    unsigned sB = (unsigned)ssrc[e0 + 4 + grp];
    sA = (e0 + grp < e1) ? sA : (unsigned)wid;
    sB = (e0 + 4 + grp < e1) ? sB : (unsigned)wid;

    for (int t = e0; t < e1; t += 8) {
        float4 a = *(const float4*)(xl + (sA << 6) + cb);
        float4 b = *(const float4*)(xl + (sB << 6) + cb);
        int tn = t + 8;
        unsigned nA = (unsigned)ssrc[tn + grp];
        unsigned nB = (unsigned)ssrc[tn + 4 + grp];
        nA = (tn + grp < e1) ? nA : (unsigned)wid;
        nB = (tn + 4 + grp < e1) ? nB : (unsigned)wid;
        bool vA = t + grp < e1;
        bool vB = t + 4 + grp < e1;

        float ux = a.x + xr4.x; ux = fmaxf(ux, 0.2f * ux);
        float uy = a.y + xr4.y; uy = fmaxf(uy, 0.2f * uy);
        float uz = a.z + xr4.z; uz = fmaxf(uz, 0.2f * uz);
        float uw = a.w + xr4.w; uw = fmaxf(uw, 0.2f * uw);
        float pa = att4.x * ux + att4.y * uy + att4.z * uz + att4.w * uw;
        pa = dpp_add<0xB1>(pa);
        pa = dpp_add<0x4E>(pa);
        if (L == 2) {
            pa = dpp_add<0x141>(pa);
            pa = dpp_add<0x140>(pa);
        }
        float pA = exp2f(pa);
        pA = vA ? pA : 0.f;
        s += pA;
        acc.x += pA * a.x; acc.y += pA * a.y; acc.z += pA * a.z; acc.w += pA * a.w;

        float vx = b.x + xr4.x; vx = fmaxf(vx, 0.2f * vx);
        float vy = b.y + xr4.y; vy = fmaxf(vy, 0.2f * vy);
        float vz = b.z + xr4.z; vz = fmaxf(vz, 0.2f * vz);
        float vw = b.w + xr4.w; vw = fmaxf(vw, 0.2f * vw);
        float pb = att4.x * vx + att4.y * vy + att4.z * vz + att4.w * vw;
        pb = dpp_add<0xB1>(pb);
        pb = dpp_add<0x4E>(pb);
        if (L == 2) {
            pb = dpp_add<0x141>(pb);
            pb = dpp_add<0x140>(pb);
        }
        float pB = exp2f(pb);
        pB = vB ? pB : 0.f;
        s += pB;
        acc.x += pB * b.x; acc.y += pB * b.y; acc.z += pB * b.z; acc.w += pB * b.w;

        sA = nA; sB = nB;
    }

    // combine the 4 edge groups (once per node)
    s += __shfl_xor(s, 16); s += __shfl_xor(s, 32);
    acc.x += __shfl_xor(acc.x, 16); acc.x += __shfl_xor(acc.x, 32);
    acc.y += __shfl_xor(acc.y, 16); acc.y += __shfl_xor(acc.y, 32);
    acc.z += __shfl_xor(acc.z, 16); acc.z += __shfl_xor(acc.z, 32);
    acc.w += __shfl_xor(acc.w, 16); acc.w += __shfl_xor(acc.w, 32);

    float inv = 1.f / (s + 1e-16f);
    if (L == 1) {
        float4 val;
        val.x = acc.x * inv + bias4.x;
        val.y = acc.y * inv + bias4.y;
        val.z = acc.z * inv + bias4.z;
        val.w = acc.w * inv + bias4.w;
        val.x = (val.x > 0.f) ? val.x : (__expf(val.x) - 1.f);
        val.y = (val.y > 0.f) ? val.y : (__expf(val.y) - 1.f);
        val.z = (val.z > 0.f) ? val.z : (__expf(val.z) - 1.f);
        val.w = (val.w > 0.f) ? val.w : (__expf(val.w) - 1.f);
        if (grp == 0) *(float4*)(out + rb + cb) = val;
    } else {
        float4 lw = *(const float4*)(linW + cb);
        float r = (acc.x * inv + bias4.x) * lw.x + (acc.y * inv + bias4.y) * lw.y +
                  (acc.z * inv + bias4.z) * lw.z + (acc.w * inv + bias4.w) * lw.w;
        r = dpp_add<0xB1>(r);
        r = dpp_add<0x4E>(r);
        r = dpp_add<0x141>(r);
        r = dpp_add<0x140>(r);
        if (lane == 0) out[wid] = r + linb[0];
    }
}

extern "C" void kernel_launch(void* const* d_in, const int* in_sizes, int n_in,
                              void* d_out, int out_size, void* d_ws, size_t ws_size,
                              hipStream_t stream) {
    const int* x = (const int*)d_in[0];
    const int* ei = (const int*)d_in[1];          // int32 marshalled
    const float* birth_tab = (const float*)d_in[2];
    const float* gender_tab = (const float*)d_in[3];
    const float* symp_tab = (const float*)d_in[4];
    const float* Wl1 = (const float*)d_in[5];
    const float* bl1 = (const float*)d_in[6];
    const float* Wr1 = (const float*)d_in[7];
    const float* br1 = (const float*)d_in[8];
    const float* att1 = (const float*)d_in[9];
    const float* bias1 = (const float*)d_in[10];
    const float* Wl2 = (const float*)d_in[11];
    const float* bl2 = (const float*)d_in[12];
    const float* Wr2 = (const float*)d_in[13];
    const float* br2 = (const float*)d_in[14];
    const float* att2 = (const float*)d_in[15];
    const float* bias2 = (const float*)d_in[16];
    const float* linW = (const float*)d_in[17];
    const float* linb = (const float*)d_in[18];
    float* outp = (float*)d_out;

    int N = in_sizes[0] / XCOLS;   // 100000
    int E = in_sizes[1] / 2;       // 1600000
    int NB = (N + BSZ - 1) >> BSH; // 782

    char* p = (char*)d_ws;
    auto alloc = [&](size_t bytes) {
        void* r = (void*)p;
        p += (bytes + 255) & ~(size_t)255;
        return r;
    };
    float* h0 = (float*)alloc((size_t)N * EMB * 4);
    float* bufA = (float*)alloc((size_t)N * EMB * 4);
    float* bufB = (float*)alloc((size_t)N * EMB * 4);
    int* bcount = (int*)alloc(MAXNB * 4);
    int* boffs = (int*)alloc((MAXNB + 1) * 4);
    int* bcursor = (int*)alloc(MAXNB * 4);
    int* offs = (int*)alloc((size_t)(N + 1) * 4);
    int* epart = (int*)alloc((size_t)E * 4);
    int* ssrc = (int*)alloc((size_t)(E + 64) * 4);   // +pad for pipelined over-read

    int ngrp = (N + 3) / 4;

    // CSR build (2-level radix partition)
    zero_kernel<<<(NB + 255) / 256, 256, 0, stream>>>(bcount, NB);
    bincount_kernel<<<512, 256, 0, stream>>>(ei, bcount, offs, E, NB, N);
    bscan_kernel<<<1, 1024, 0, stream>>>(bcount, boffs, bcursor, NB);
    partition_kernel<<<(E + PCHUNK - 1) / PCHUNK, 256, 0, stream>>>(ei, bcursor, epart, E, NB);
    finalize_kernel<<<NB, 256, 0, stream>>>(epart, boffs, offs, ssrc, N);

    // node pipeline
    embed_kernel<<<ngrp, 256, 0, stream>>>(x, birth_tab, gender_tab, symp_tab, h0, N);
    gemm_dual_kernel<<<1024, GT, 0, stream>>>(h0, Wl1, bl1, Wr1, br1, bufA, bufB, N);
    gat_kernel<1><<<ngrp, 256, 0, stream>>>(bufA, bufB, offs, ssrc, att1, bias1,
                                            nullptr, nullptr, h0, N);
    gemm_dual_kernel<<<1024, GT, 0, stream>>>(h0, Wl2, bl2, Wr2, br2, bufA, bufB, N);
    gat_kernel<2><<<ngrp, 256, 0, stream>>>(bufA, bufB, offs, ssrc, att2, bias2,
                                            linW, linb, outp, N);
}

// Round 10
// 292.117 us; speedup vs baseline: 7.8267x; 7.8267x over previous
//
#include <hip/hip_runtime.h>
#include <hip/hip_bf16.h>

#define EMB 64
#define XCOLS 20
#define NSYMP 15
#define BSH 7
#define BSZ 128          // nodes per bucket (1<<BSH)
#define MAXNB 1024       // supports N <= 131072
#define PCHUNK 4096
#define GT 512           // gemm block threads

__global__ void zero_kernel(int* __restrict__ p, int n) {
    int i = blockIdx.x * blockDim.x + threadIdx.x;
    if (i < n) p[i] = 0;
}

// ---------------- embedding ----------------
__global__ void embed_kernel(const int* __restrict__ x,
                             const float* __restrict__ bt,
                             const float* __restrict__ gt,
                             const float* __restrict__ st,
                             float* __restrict__ h0, int N) {
    __shared__ int xs[4 * XCOLS];
    int node = blockIdx.x * 4 + (threadIdx.x >> 6);
    int d = threadIdx.x & 63;
    if (threadIdx.x < 4 * XCOLS) {
        int n2 = blockIdx.x * 4 + threadIdx.x / XCOLS;
        int c = threadIdx.x % XCOLS;
        xs[threadIdx.x] = (n2 < N) ? x[n2 * XCOLS + c] : 0;
    }
    __syncthreads();
    if (node >= N) return;
    const int* xr = &xs[(threadIdx.x >> 6) * XCOLS];
    int bi = xr[1] + 2 * xr[2] + 3 * xr[3];   // argmax of one-hot
    int g = xr[4];
    float f = 0.f;
#pragma unroll
    for (int j = 0; j < NSYMP; ++j) {
        int sj = xr[5 + j];
        f += st[(j * 3 + sj) * EMB + d];
    }
    float val = (bt[bi * EMB + d] + gt[g * EMB + d] + f * (1.f / 15.f)) * (1.f / 3.f);
    h0[node * EMB + d] = val;
}

// ---------------- dual GEMM: outL = h@Wl+bl, outR = h@Wr+br (64x64 weights) ----
// wp[k/2][d][4] = (Wl[2k][d],Wr[2k][d],Wl[2k+1][d],Wr[2k+1][d]): one
// ds_read_b128 feeds 2 k-steps of BOTH gemms. 2 nodes/wave, float2 broadcast
// h reads: 3 LDS reads per 8 FMAs. __launch_bounds__(512,4) caps VGPR at 128
// and unroll 4 keeps in-flight LDS loads ~32 dwords -> NO scratch spill
// (R9 lesson: 512 threads w/o bounds -> 64-VGPR cap + full unroll = 4.3 GB
// of spill traffic, 14x slowdown).
__global__ __launch_bounds__(GT, 4)
void gemm_dual_kernel(const float* __restrict__ h,
                      const float* __restrict__ Wl, const float* __restrict__ bl,
                      const float* __restrict__ Wr, const float* __restrict__ br,
                      float* __restrict__ outL, float* __restrict__ outR, int N) {
    __shared__ float wp[EMB / 2][EMB][4];   // 32 KB
    __shared__ float hr[2][16][EMB];        // 8 KB (double-buffered 16-node tile)
    for (int i = threadIdx.x; i < EMB * EMB; i += GT) {
        int k = i >> 6, d = i & 63;
        wp[k >> 1][d][(k & 1) * 2 + 0] = Wl[i];
        wp[k >> 1][d][(k & 1) * 2 + 1] = Wr[i];
    }
    int w = threadIdx.x >> 6;       // wave 0..7 -> local nodes 2w, 2w+1
    int d = threadIdx.x & 63;
    int ngroups = (N + 15) / 16;
    size_t total = (size_t)N * EMB;
    float blv = bl[d], brv = br[d];
    // preload tile 0
    if (threadIdx.x < 256 && blockIdx.x < ngroups) {
        size_t idx = (size_t)blockIdx.x * 1024 + threadIdx.x * 4;
        float4 v = {0.f, 0.f, 0.f, 0.f};
        if (idx + 3 < total) v = *(const float4*)(h + idx);
        else for (int j = 0; j < 4; ++j) ((float*)&v)[j] = (idx + j < total) ? h[idx + j] : 0.f;
        ((float4*)&hr[0][0][0])[threadIdx.x] = v;
    }
    int buf = 0;
    for (int g = blockIdx.x; g < ngroups; g += gridDim.x) {
        __syncthreads();                 // hr[buf] + wp ready
        int gn = g + gridDim.x;
        if (gn < ngroups && threadIdx.x < 256) {
            size_t idx = (size_t)gn * 1024 + threadIdx.x * 4;
            float4 v = {0.f, 0.f, 0.f, 0.f};
            if (idx + 3 < total) v = *(const float4*)(h + idx);
            else for (int j = 0; j < 4; ++j) ((float*)&v)[j] = (idx + j < total) ? h[idx + j] : 0.f;
            ((float4*)&hr[buf ^ 1][0][0])[threadIdx.x] = v;
        }
        const float* h0p = &hr[buf][2 * w][0];
        const float* h1p = &hr[buf][2 * w + 1][0];
        float l0 = blv, r0 = brv, l1 = blv, r1 = brv;
#pragma unroll 4
        for (int kk = 0; kk < EMB / 2; ++kk) {
            float4 wv = *(const float4*)&wp[kk][d][0];
            float2 h0 = *(const float2*)(h0p + kk * 2);
            float2 h1 = *(const float2*)(h1p + kk * 2);
            l0 += h0.x * wv.x + h0.y * wv.z;
            r0 += h0.x * wv.y + h0.y * wv.w;
            l1 += h1.x * wv.x + h1.y * wv.z;
            r1 += h1.x * wv.y + h1.y * wv.w;
        }
        int node0 = g * 16 + 2 * w;
        int node1 = node0 + 1;
        if (node0 < N) { outL[node0 * EMB + d] = l0; outR[node0 * EMB + d] = r0; }
        if (node1 < N) { outL[node1 * EMB + d] = l1; outR[node1 * EMB + d] = r1; }
        buf ^= 1;
    }
}

// ---------------- CSR build via 2-level radix partition ----------------
__global__ void bincount_kernel(const int* __restrict__ ei, int* __restrict__ bcount,
                                int* __restrict__ offs, int E, int NB, int N) {
    __shared__ int lh[MAXNB];
    for (int j = threadIdx.x; j < NB; j += 256) lh[j] = 0;
    __syncthreads();
    for (int i = blockIdx.x * 256 + threadIdx.x; i < E; i += gridDim.x * 256)
        atomicAdd(&lh[ei[E + i] >> BSH], 1);
    __syncthreads();
    for (int j = threadIdx.x; j < NB; j += 256)
        if (lh[j]) atomicAdd(&bcount[j], lh[j]);
    if (blockIdx.x == 0 && threadIdx.x == 0) offs[N] = E;
}

__global__ void bscan_kernel(const int* __restrict__ bcount, int* __restrict__ boffs,
                             int* __restrict__ bcursor, int NB) {
    __shared__ int s[1024];
    int t = threadIdx.x;
    int v0 = (t < NB) ? bcount[t] : 0;
    s[t] = v0;
    __syncthreads();
    for (int off = 1; off < 1024; off <<= 1) {
        int v = (t >= off) ? s[t - off] : 0;
        __syncthreads();
        s[t] += v;
        __syncthreads();
    }
    if (t < NB) {
        boffs[t + 1] = s[t];
        bcursor[t] = s[t] - v0;
    }
    if (t == 0) boffs[0] = 0;
}

__global__ void partition_kernel(const int* __restrict__ ei, int* __restrict__ bcursor,
                                 int* __restrict__ epart, int E, int NB) {
    __shared__ int lh[MAXNB];
    for (int j = threadIdx.x; j < NB; j += 256) lh[j] = 0;
    __syncthreads();
    int base = blockIdx.x * PCHUNK;
    int end = min(E, base + PCHUNK);
    for (int i = base + threadIdx.x; i < end; i += 256)
        atomicAdd(&lh[ei[E + i] >> BSH], 1);
    __syncthreads();
    for (int j = threadIdx.x; j < NB; j += 256) {
        int c = lh[j];
        lh[j] = c ? atomicAdd(&bcursor[j], c) : 0;
    }
    __syncthreads();
    for (int i = base + threadIdx.x; i < end; i += 256) {
        int dst = ei[E + i];
        int src = ei[i];
        int slot = atomicAdd(&lh[dst >> BSH], 1);
        epart[slot] = (src << BSH) | (dst & (BSZ - 1));
    }
}

// per-wave sub-histograms/sub-cursors to cut LDS-atomic contention 4x
__global__ void finalize_kernel(const int* __restrict__ epart, const int* __restrict__ boffs,
                                int* __restrict__ offs, int* __restrict__ ssrc, int N) {
    __shared__ int deg4[4][BSZ];
    __shared__ int pos[BSZ];
    __shared__ int cur4[4][BSZ];
    int b = blockIdx.x;
    int t = threadIdx.x;
    int w = t >> 6;
    int n0 = b << BSH;
    int r0 = boffs[b], r1 = boffs[b + 1];
    ((int*)deg4)[t] = 0;
    ((int*)deg4)[t + 256] = 0;
    __syncthreads();
    for (int e = r0 + t; e < r1; e += 256)
        atomicAdd(&deg4[w][epart[e] & (BSZ - 1)], 1);
    __syncthreads();
    int d0 = 0, d1 = 0, d2 = 0, sum = 0;
    if (t < BSZ) {
        d0 = deg4[0][t]; d1 = deg4[1][t]; d2 = deg4[2][t];
        sum = d0 + d1 + d2 + deg4[3][t];
        pos[t] = sum;
    }
    __syncthreads();
    for (int off = 1; off < BSZ; off <<= 1) {
        int v = (t < BSZ && t >= off) ? pos[t - off] : 0;
        __syncthreads();
        if (t < BSZ) pos[t] += v;
        __syncthreads();
    }
    if (t < BSZ) {
        int base = r0 + pos[t] - sum;
        int node = n0 + t;
        if (node < N) offs[node] = base;
        cur4[0][t] = base;
        cur4[1][t] = base + d0;
        cur4[2][t] = base + d0 + d1;
        cur4[3][t] = base + d0 + d1 + d2;
    }
    __syncthreads();
    for (int e = r0 + t; e < r1; e += 256) {
        int v = epart[e];
        int s = atomicAdd(&cur4[w][v & (BSZ - 1)], 1);
        ssrc[s] = v >> BSH;
    }
}

// ---------------- DPP cross-lane add (VALU pipe; compiler handles hazards) --
template <int CTRL>
__device__ __forceinline__ float dpp_add(float v) {
    union { float f; int i; } u, r;
    u.f = v;
    r.i = __builtin_amdgcn_update_dpp(0, u.i, CTRL, 0xF, 0xF, true);
    return v + r.f;
}

// ---------------- GATv2 layer: 8 edges per wave iteration, pipelined --------
template <int L>
__global__ void gat_kernel(const float* __restrict__ xl, const float* __restrict__ xr,
                           const int* __restrict__ offs, const int* __restrict__ ssrc,
                           const float* __restrict__ att, const float* __restrict__ bias,
                           const float* __restrict__ linW, const float* __restrict__ linb,
                           float* __restrict__ out, int N) {
    int wid = blockIdx.x * 4 + (threadIdx.x >> 6);
    int lane = threadIdx.x & 63;
    if (wid >= N) return;
    int grp = lane >> 4;          // edge slot within the 4-wide half-batch
    int li = lane & 15;           // float4 channel slot
    unsigned cb = (unsigned)li << 2;

    const float LOG2E = 1.4426950408889634f;
    float4 att4 = *(const float4*)(att + cb);
    att4.x *= LOG2E; att4.y *= LOG2E; att4.z *= LOG2E; att4.w *= LOG2E;
    float4 bias4 = *(const float4*)(bias + cb);
    unsigned rb = (unsigned)wid << 6;
    float4 xr4 = *(const float4*)(xr + rb + cb);

    int e0 = offs[wid], e1 = offs[wid + 1];

    float s = 0.f;
    float4 acc = {0.f, 0.f, 0.f, 0.f};

    // self-loop: computed by all groups, counted by group 0 only
    {
        float4 a = *(const float4*)(xl + rb + cb);
        float ux = a.x + xr4.x; ux = fmaxf(ux, 0.2f * ux);
        float uy = a.y + xr4.y; uy = fmaxf(uy, 0.2f * uy);
        float uz = a.z + xr4.z; uz = fmaxf(uz, 0.2f * uz);
        float uw = a.w + xr4.w; uw = fmaxf(uw, 0.2f * uw);
        float part = att4.x * ux + att4.y * uy + att4.z * uz + att4.w * uw;
        part = dpp_add<0xB1>(part);
        part = dpp_add<0x4E>(part);
        if (L == 2) {
            part = dpp_add<0x141>(part);
            part = dpp_add<0x140>(part);
        }
        float p = exp2f(part);
        p = (grp == 0) ? p : 0.f;
        s += p;
        acc.x += p * a.x; acc.y += p * a.y; acc.z += p * a.z; acc.w += p * a.w;
    }

    // prologue: indices for first batch (ssrc padded -> unconditional loads OK)
    unsigned sA = (unsigned)ssrc[e0 + grp];
    unsigned sB = (unsigned)ssrc[e0 + 4 + grp];
    sA = (e0 + grp < e1) ? sA : (unsigned)wid;
    sB = (e0 + 4 + grp < e1) ? sB : (unsigned)wid;

    for (int t = e0; t < e1; t += 8) {
        float4 a = *(const float4*)(xl + (sA << 6) + cb);
        float4 b = *(const float4*)(xl + (sB << 6) + cb);
        int tn = t + 8;
        unsigned nA = (unsigned)ssrc[tn + grp];
        unsigned nB = (unsigned)ssrc[tn + 4 + grp];
        nA = (tn + grp < e1) ? nA : (unsigned)wid;
        nB = (tn + 4 + grp < e1) ? nB : (unsigned)wid;
        bool vA = t + grp < e1;
        bool vB = t + 4 + grp < e1;

        float ux = a.x + xr4.x; ux = fmaxf(ux, 0.2f * ux);
        float uy = a.y + xr4.y; uy = fmaxf(uy, 0.2f * uy);
        float uz = a.z + xr4.z; uz = fmaxf(uz, 0.2f * uz);
        float uw = a.w + xr4.w; uw = fmaxf(uw, 0.2f * uw);
        float pa = att4.x * ux + att4.y * uy + att4.z * uz + att4.w * uw;
        pa = dpp_add<0xB1>(pa);
        pa = dpp_add<0x4E>(pa);
        if (L == 2) {
            pa = dpp_add<0x141>(pa);
            pa = dpp_add<0x140>(pa);
        }
        float pA = exp2f(pa);
        pA = vA ? pA : 0.f;
        s += pA;
        acc.x += pA * a.x; acc.y += pA * a.y; acc.z += pA * a.z; acc.w += pA * a.w;

        float vx = b.x + xr4.x; vx = fmaxf(vx, 0.2f * vx);
        float vy = b.y + xr4.y; vy = fmaxf(vy, 0.2f * vy);
        float vz = b.z + xr4.z; vz = fmaxf(vz, 0.2f * vz);
        float vw = b.w + xr4.w; vw = fmaxf(vw, 0.2f * vw);
        float pb = att4.x * vx + att4.y * vy + att4.z * vz + att4.w * vw;
        pb = dpp_add<0xB1>(pb);
        pb = dpp_add<0x4E>(pb);
        if (L == 2) {
            pb = dpp_add<0x141>(pb);
            pb = dpp_add<0x140>(pb);
        }
        float pB = exp2f(pb);
        pB = vB ? pB : 0.f;
        s += pB;
        acc.x += pB * b.x; acc.y += pB * b.y; acc.z += pB * b.z; acc.w += pB * b.w;

        sA = nA; sB = nB;
    }

    // combine the 4 edge groups (once per node)
    s += __shfl_xor(s, 16); s += __shfl_xor(s, 32);
    acc.x += __shfl_xor(acc.x, 16); acc.x += __shfl_xor(acc.x, 32);
    acc.y += __shfl_xor(acc.y, 16); acc.y += __shfl_xor(acc.y, 32);
    acc.z += __shfl_xor(acc.z, 16); acc.z += __shfl_xor(acc.z, 32);
    acc.w += __shfl_xor(acc.w, 16); acc.w += __shfl_xor(acc.w, 32);

    float inv = 1.f / (s + 1e-16f);
    if (L == 1) {
        float4 val;
        val.x = acc.x * inv + bias4.x;
        val.y = acc.y * inv + bias4.y;
        val.z = acc.z * inv + bias4.z;
        val.w = acc.w * inv + bias4.w;
        val.x = (val.x > 0.f) ? val.x : (__expf(val.x) - 1.f);
        val.y = (val.y > 0.f) ? val.y : (__expf(val.y) - 1.f);
        val.z = (val.z > 0.f) ? val.z : (__expf(val.z) - 1.f);
        val.w = (val.w > 0.f) ? val.w : (__expf(val.w) - 1.f);
        if (grp == 0) *(float4*)(out + rb + cb) = val;
    } else {
        float4 lw = *(const float4*)(linW + cb);
        float r = (acc.x * inv + bias4.x) * lw.x + (acc.y * inv + bias4.y) * lw.y +
                  (acc.z * inv + bias4.z) * lw.z + (acc.w * inv + bias4.w) * lw.w;
        r = dpp_add<0xB1>(r);
        r = dpp_add<0x4E>(r);
        r = dpp_add<0x141>(r);
        r = dpp_add<0x140>(r);
        if (lane == 0) out[wid] = r + linb[0];
    }
}

extern "C" void kernel_launch(void* const* d_in, const int* in_sizes, int n_in,
                              void* d_out, int out_size, void* d_ws, size_t ws_size,
                              hipStream_t stream) {
    const int* x = (const int*)d_in[0];
    const int* ei = (const int*)d_in[1];          // int32 marshalled
    const float* birth_tab = (const float*)d_in[2];
    const float* gender_tab = (const float*)d_in[3];
    const float* symp_tab = (const float*)d_in[4];
    const float* Wl1 = (const float*)d_in[5];
    const float* bl1 = (const float*)d_in[6];
    const float* Wr1 = (const float*)d_in[7];
    const float* br1 = (const float*)d_in[8];
    const float* att1 = (const float*)d_in[9];
    const float* bias1 = (const float*)d_in[10];
    const float* Wl2 = (const float*)d_in[11];
    const float* bl2 = (const float*)d_in[12];
    const float* Wr2 = (const float*)d_in[13];
    const float* br2 = (const float*)d_in[14];
    const float* att2 = (const float*)d_in[15];
    const float* bias2 = (const float*)d_in[16];
    const float* linW = (const float*)d_in[17];
    const float* linb = (const float*)d_in[18];
    float* outp = (float*)d_out;

    int N = in_sizes[0] / XCOLS;   // 100000
    int E = in_sizes[1] / 2;       // 1600000
    int NB = (N + BSZ - 1) >> BSH; // 782

    char* p = (char*)d_ws;
    auto alloc = [&](size_t bytes) {
        void* r = (void*)p;
        p += (bytes + 255) & ~(size_t)255;
        return r;
    };
    float* h0 = (float*)alloc((size_t)N * EMB * 4);
    float* bufA = (float*)alloc((size_t)N * EMB * 4);
    float* bufB = (float*)alloc((size_t)N * EMB * 4);
    int* bcount = (int*)alloc(MAXNB * 4);
    int* boffs = (int*)alloc((MAXNB + 1) * 4);
    int* bcursor = (int*)alloc(MAXNB * 4);
    int* offs = (int*)alloc((size_t)(N + 1) * 4);
    int* epart = (int*)alloc((size_t)E * 4);
    int* ssrc = (int*)alloc((size_t)(E + 64) * 4);   // +pad for pipelined over-read

    int ngrp = (N + 3) / 4;

    // CSR build (2-level radix partition)
    zero_kernel<<<(NB + 255) / 256, 256, 0, stream>>>(bcount, NB);
    bincount_kernel<<<512, 256, 0, stream>>>(ei, bcount, offs, E, NB, N);
    bscan_kernel<<<1, 1024, 0, stream>>>(bcount, boffs, bcursor, NB);
    partition_kernel<<<(E + PCHUNK - 1) / PCHUNK, 256, 0, stream>>>(ei, bcursor, epart, E, NB);
    finalize_kernel<<<NB, 256, 0, stream>>>(epart, boffs, offs, ssrc, N);

    // node pipeline
    embed_kernel<<<ngrp, 256, 0, stream>>>(x, birth_tab, gender_tab, symp_tab, h0, N);
    gemm_dual_kernel<<<1024, GT, 0, stream>>>(h0, Wl1, bl1, Wr1, br1, bufA, bufB, N);
    gat_kernel<1><<<ngrp, 256, 0, stream>>>(bufA, bufB, offs, ssrc, att1, bias1,
                                            nullptr, nullptr, h0, N);
    gemm_dual_kernel<<<1024, GT, 0, stream>>>(h0, Wl2, bl2, Wr2, br2, bufA, bufB, N);
    gat_kernel<2><<<ngrp, 256, 0, stream>>>(bufA, bufB, offs, ssrc, att2, bias2,
                                            linW, linb, outp, N);
}

// Round 11
// 279.862 us; speedup vs baseline: 8.1694x; 1.0438x over previous
//
#include <hip/hip_runtime.h>
#include <hip/hip_bf16.h>

#define EMB 64
#define XCOLS 20
#define NSYMP 15
#define BSH 7
#define BSZ 128          // nodes per bucket (1<<BSH)
#define MAXNB 1024       // supports N <= 131072
#define PCHUNK 4096

__global__ void zero_kernel(int* __restrict__ p, int n) {
    int i = blockIdx.x * blockDim.x + threadIdx.x;
    if (i < n) p[i] = 0;
}

// ---------------- embedding ----------------
__global__ void embed_kernel(const int* __restrict__ x,
                             const float* __restrict__ bt,
                             const float* __restrict__ gt,
                             const float* __restrict__ st,
                             float* __restrict__ h0, int N) {
    __shared__ int xs[4 * XCOLS];
    int node = blockIdx.x * 4 + (threadIdx.x >> 6);
    int d = threadIdx.x & 63;
    if (threadIdx.x < 4 * XCOLS) {
        int n2 = blockIdx.x * 4 + threadIdx.x / XCOLS;
        int c = threadIdx.x % XCOLS;
        xs[threadIdx.x] = (n2 < N) ? x[n2 * XCOLS + c] : 0;
    }
    __syncthreads();
    if (node >= N) return;
    const int* xr = &xs[(threadIdx.x >> 6) * XCOLS];
    int bi = xr[1] + 2 * xr[2] + 3 * xr[3];   // argmax of one-hot
    int g = xr[4];
    float f = 0.f;
#pragma unroll
    for (int j = 0; j < NSYMP; ++j) {
        int sj = xr[5 + j];
        f += st[(j * 3 + sj) * EMB + d];
    }
    float val = (bt[bi * EMB + d] + gt[g * EMB + d] + f * (1.f / 15.f)) * (1.f / 3.f);
    h0[node * EMB + d] = val;
}

// ---------------- dual GEMM v3: register-resident weights ----------------
// lane d holds Wl[:,d], Wr[:,d] in 128 VGPRs (loaded once per wave, coalesced).
// Per node: 16 wave-uniform float4 broadcast loads of the h row (readfirstlane
// -> one transaction each, L2-resident), 128 FMAs with 4 accumulator chains.
// No LDS, no barriers, no weight re-streaming (R10: LDS-streamed weights cost
// ~1.6 GB of LDS reads -> 49us; pure-FMA floor is 10.4us).
__global__ __launch_bounds__(256, 3)
void gemm_dual_kernel(const float* __restrict__ h,
                      const float* __restrict__ Wl, const float* __restrict__ bl,
                      const float* __restrict__ Wr, const float* __restrict__ br,
                      float* __restrict__ outL, float* __restrict__ outR, int N) {
    int lane = threadIdx.x & 63;
    int wv = threadIdx.x >> 6;
    float wl[EMB], wr[EMB];
#pragma unroll
    for (int k = 0; k < EMB; ++k) {
        wl[k] = Wl[k * EMB + lane];
        wr[k] = Wr[k * EMB + lane];
    }
    float blv = bl[lane], brv = br[lane];
    int wstride = gridDim.x * 4;
    for (int node = blockIdx.x * 4 + wv; node < N; node += wstride) {
        int un = __builtin_amdgcn_readfirstlane(node);
        const float* hrow = h + (size_t)un * EMB;
        float l0 = blv, l1 = 0.f, r0 = brv, r1 = 0.f;
#pragma unroll
        for (int kk = 0; kk < EMB / 4; ++kk) {
            float4 hv = *(const float4*)(hrow + kk * 4);
            l0 = fmaf(hv.x, wl[kk * 4 + 0], l0);
            r0 = fmaf(hv.x, wr[kk * 4 + 0], r0);
            l1 = fmaf(hv.y, wl[kk * 4 + 1], l1);
            r1 = fmaf(hv.y, wr[kk * 4 + 1], r1);
            l0 = fmaf(hv.z, wl[kk * 4 + 2], l0);
            r0 = fmaf(hv.z, wr[kk * 4 + 2], r0);
            l1 = fmaf(hv.w, wl[kk * 4 + 3], l1);
            r1 = fmaf(hv.w, wr[kk * 4 + 3], r1);
        }
        outL[(size_t)node * EMB + lane] = l0 + l1;
        outR[(size_t)node * EMB + lane] = r0 + r1;
    }
}

// ---------------- CSR build via 2-level radix partition ----------------
__global__ void bincount_kernel(const int* __restrict__ ei, int* __restrict__ bcount,
                                int* __restrict__ offs, int E, int NB, int N) {
    __shared__ int lh[MAXNB];
    for (int j = threadIdx.x; j < NB; j += 256) lh[j] = 0;
    __syncthreads();
    for (int i = blockIdx.x * 256 + threadIdx.x; i < E; i += gridDim.x * 256)
        atomicAdd(&lh[ei[E + i] >> BSH], 1);
    __syncthreads();
    for (int j = threadIdx.x; j < NB; j += 256)
        if (lh[j]) atomicAdd(&bcount[j], lh[j]);
    if (blockIdx.x == 0 && threadIdx.x == 0) offs[N] = E;
}

__global__ void bscan_kernel(const int* __restrict__ bcount, int* __restrict__ boffs,
                             int* __restrict__ bcursor, int NB) {
    __shared__ int s[1024];
    int t = threadIdx.x;
    int v0 = (t < NB) ? bcount[t] : 0;
    s[t] = v0;
    __syncthreads();
    for (int off = 1; off < 1024; off <<= 1) {
        int v = (t >= off) ? s[t - off] : 0;
        __syncthreads();
        s[t] += v;
        __syncthreads();
    }
    if (t < NB) {
        boffs[t + 1] = s[t];
        bcursor[t] = s[t] - v0;
    }
    if (t == 0) boffs[0] = 0;
}

__global__ void partition_kernel(const int* __restrict__ ei, int* __restrict__ bcursor,
                                 int* __restrict__ epart, int E, int NB) {
    __shared__ int lh[MAXNB];
    for (int j = threadIdx.x; j < NB; j += 256) lh[j] = 0;
    __syncthreads();
    int base = blockIdx.x * PCHUNK;
    int end = min(E, base + PCHUNK);
    for (int i = base + threadIdx.x; i < end; i += 256)
        atomicAdd(&lh[ei[E + i] >> BSH], 1);
    __syncthreads();
    for (int j = threadIdx.x; j < NB; j += 256) {
        int c = lh[j];
        lh[j] = c ? atomicAdd(&bcursor[j], c) : 0;
    }
    __syncthreads();
    for (int i = base + threadIdx.x; i < end; i += 256) {
        int dst = ei[E + i];
        int src = ei[i];
        int slot = atomicAdd(&lh[dst >> BSH], 1);
        epart[slot] = (src << BSH) | (dst & (BSZ - 1));
    }
}

// per-wave sub-histograms/sub-cursors to cut LDS-atomic contention 4x
__global__ void finalize_kernel(const int* __restrict__ epart, const int* __restrict__ boffs,
                                int* __restrict__ offs, int* __restrict__ ssrc, int N) {
    __shared__ int deg4[4][BSZ];
    __shared__ int pos[BSZ];
    __shared__ int cur4[4][BSZ];
    int b = blockIdx.x;
    int t = threadIdx.x;
    int w = t >> 6;
    int n0 = b << BSH;
    int r0 = boffs[b], r1 = boffs[b + 1];
    ((int*)deg4)[t] = 0;
    ((int*)deg4)[t + 256] = 0;
    __syncthreads();
    for (int e = r0 + t; e < r1; e += 256)
        atomicAdd(&deg4[w][epart[e] & (BSZ - 1)], 1);
    __syncthreads();
    int d0 = 0, d1 = 0, d2 = 0, sum = 0;
    if (t < BSZ) {
        d0 = deg4[0][t]; d1 = deg4[1][t]; d2 = deg4[2][t];
        sum = d0 + d1 + d2 + deg4[3][t];
        pos[t] = sum;
    }
    __syncthreads();
    for (int off = 1; off < BSZ; off <<= 1) {
        int v = (t < BSZ && t >= off) ? pos[t - off] : 0;
        __syncthreads();
        if (t < BSZ) pos[t] += v;
        __syncthreads();
    }
    if (t < BSZ) {
        int base = r0 + pos[t] - sum;
        int node = n0 + t;
        if (node < N) offs[node] = base;
        cur4[0][t] = base;
        cur4[1][t] = base + d0;
        cur4[2][t] = base + d0 + d1;
        cur4[3][t] = base + d0 + d1 + d2;
    }
    __syncthreads();
    for (int e = r0 + t; e < r1; e += 256) {
        int v = epart[e];
        int s = atomicAdd(&cur4[w][v & (BSZ - 1)], 1);
        ssrc[s] = v >> BSH;
    }
}

// ---------------- DPP cross-lane add (VALU pipe; compiler handles hazards) --
template <int CTRL>
__device__ __forceinline__ float dpp_add(float v) {
    union { float f; int i; } u, r;
    u.f = v;
    r.i = __builtin_amdgcn_update_dpp(0, u.i, CTRL, 0xF, 0xF, true);
    return v + r.f;
}

// ---------------- GATv2 layer: 8 edges per wave iteration, pipelined --------
template <int L>
__global__ void gat_kernel(const float* __restrict__ xl, const float* __restrict__ xr,
                           const int* __restrict__ offs, const int* __restrict__ ssrc,
                           const float* __restrict__ att, const float* __restrict__ bias,
                           const float* __restrict__ linW, const float* __restrict__ linb,
                           float* __restrict__ out, int N) {
    int wid = blockIdx.x * 4 + (threadIdx.x >> 6);
    int lane = threadIdx.x & 63;
    if (wid >= N) return;
    int grp = lane >> 4;          // edge slot within the 4-wide half-batch
    int li = lane & 15;           // float4 channel slot
    unsigned cb = (unsigned)li << 2;

    const float LOG2E = 1.4426950408889634f;
    float4 att4 = *(const float4*)(att + cb);
    att4.x *= LOG2E; att4.y *= LOG2E; att4.z *= LOG2E; att4.w *= LOG2E;
    float4 bias4 = *(const float4*)(bias + cb);
    unsigned rb = (unsigned)wid << 6;
    float4 xr4 = *(const float4*)(xr + rb + cb);

    int e0 = offs[wid], e1 = offs[wid + 1];

    float s = 0.f;
    float4 acc = {0.f, 0.f, 0.f, 0.f};

    // self-loop: computed by all groups, counted by group 0 only
    {
        float4 a = *(const float4*)(xl + rb + cb);
        float ux = a.x + xr4.x; ux = fmaxf(ux, 0.2f * ux);
        float uy = a.y + xr4.y; uy = fmaxf(uy, 0.2f * uy);
        float uz = a.z + xr4.z; uz = fmaxf(uz, 0.2f * uz);
        float uw = a.w + xr4.w; uw = fmaxf(uw, 0.2f * uw);
        float part = att4.x * ux + att4.y * uy + att4.z * uz + att4.w * uw;
        part = dpp_add<0xB1>(part);
        part = dpp_add<0x4E>(part);
        if (L == 2) {
            part = dpp_add<0x141>(part);
            part = dpp_add<0x140>(part);
        }
        float p = exp2f(part);
        p = (grp == 0) ? p : 0.f;
        s += p;
        acc.x += p * a.x; acc.y += p * a.y; acc.z += p * a.z; acc.w += p * a.w;
    }

    // prologue: indices for first batch (ssrc padded -> unconditional loads OK)
    unsigned sA = (unsigned)ssrc[e0 + grp];
    unsigned sB = (unsigned)ssrc[e0 + 4 + grp];
    sA = (e0 + grp < e1) ? sA : (unsigned)wid;
    sB = (e0 + 4 + grp < e1) ? sB : (unsigned)wid;

    for (int t = e0; t < e1; t += 8) {
        float4 a = *(const float4*)(xl + (sA << 6) + cb);
        float4 b = *(const float4*)(xl + (sB << 6) + cb);
        int tn = t + 8;
        unsigned nA = (unsigned)ssrc[tn + grp];
        unsigned nB = (unsigned)ssrc[tn + 4 + grp];
        nA = (tn + grp < e1) ? nA : (unsigned)wid;
        nB = (tn + 4 + grp < e1) ? nB : (unsigned)wid;
        bool vA = t + grp < e1;
        bool vB = t + 4 + grp < e1;

        float ux = a.x + xr4.x; ux = fmaxf(ux, 0.2f * ux);
        float uy = a.y + xr4.y; uy = fmaxf(uy, 0.2f * uy);
        float uz = a.z + xr4.z; uz = fmaxf(uz, 0.2f * uz);
        float uw = a.w + xr4.w; uw = fmaxf(uw, 0.2f * uw);
        float pa = att4.x * ux + att4.y * uy + att4.z * uz + att4.w * uw;
        pa = dpp_add<0xB1>(pa);
        pa = dpp_add<0x4E>(pa);
        if (L == 2) {
            pa = dpp_add<0x141>(pa);
            pa = dpp_add<0x140>(pa);
        }
        float pA = exp2f(pa);
        pA = vA ? pA : 0.f;
        s += pA;
        acc.x += pA * a.x; acc.y += pA * a.y; acc.z += pA * a.z; acc.w += pA * a.w;

        float vx = b.x + xr4.x; vx = fmaxf(vx, 0.2f * vx);
        float vy = b.y + xr4.y; vy = fmaxf(vy, 0.2f * vy);
        float vz = b.z + xr4.z; vz = fmaxf(vz, 0.2f * vz);
        float vw = b.w + xr4.w; vw = fmaxf(vw, 0.2f * vw);
        float pb = att4.x * vx + att4.y * vy + att4.z * vz + att4.w * vw;
        pb = dpp_add<0xB1>(pb);
        pb = dpp_add<0x4E>(pb);
        if (L == 2) {
            pb = dpp_add<0x141>(pb);
            pb = dpp_add<0x140>(pb);
        }
        float pB = exp2f(pb);
        pB = vB ? pB : 0.f;
        s += pB;
        acc.x += pB * b.x; acc.y += pB * b.y; acc.z += pB * b.z; acc.w += pB * b.w;

        sA = nA; sB = nB;
    }

    // combine the 4 edge groups (once per node)
    s += __shfl_xor(s, 16); s += __shfl_xor(s, 32);
    acc.x += __shfl_xor(acc.x, 16); acc.x += __shfl_xor(acc.x, 32);
    acc.y += __shfl_xor(acc.y, 16); acc.y += __shfl_xor(acc.y, 32);
    acc.z += __shfl_xor(acc.z, 16); acc.z += __shfl_xor(acc.z, 32);
    acc.w += __shfl_xor(acc.w, 16); acc.w += __shfl_xor(acc.w, 32);

    float inv = 1.f / (s + 1e-16f);
    if (L == 1) {
        float4 val;
        val.x = acc.x * inv + bias4.x;
        val.y = acc.y * inv + bias4.y;
        val.z = acc.z * inv + bias4.z;
        val.w = acc.w * inv + bias4.w;
        val.x = (val.x > 0.f) ? val.x : (__expf(val.x) - 1.f);
        val.y = (val.y > 0.f) ? val.y : (__expf(val.y) - 1.f);
        val.z = (val.z > 0.f) ? val.z : (__expf(val.z) - 1.f);
        val.w = (val.w > 0.f) ? val.w : (__expf(val.w) - 1.f);
        if (grp == 0) *(float4*)(out + rb + cb) = val;
    } else {
        float4 lw = *(const float4*)(linW + cb);
        float r = (acc.x * inv + bias4.x) * lw.x + (acc.y * inv + bias4.y) * lw.y +
                  (acc.z * inv + bias4.z) * lw.z + (acc.w * inv + bias4.w) * lw.w;
        r = dpp_add<0xB1>(r);
        r = dpp_add<0x4E>(r);
        r = dpp_add<0x141>(r);
        r = dpp_add<0x140>(r);
        if (lane == 0) out[wid] = r + linb[0];
    }
}

extern "C" void kernel_launch(void* const* d_in, const int* in_sizes, int n_in,
                              void* d_out, int out_size, void* d_ws, size_t ws_size,
                              hipStream_t stream) {
    const int* x = (const int*)d_in[0];
    const int* ei = (const int*)d_in[1];          // int32 marshalled
    const float* birth_tab = (const float*)d_in[2];
    const float* gender_tab = (const float*)d_in[3];
    const float* symp_tab = (const float*)d_in[4];
    const float* Wl1 = (const float*)d_in[5];
    const float* bl1 = (const float*)d_in[6];
    const float* Wr1 = (const float*)d_in[7];
    const float* br1 = (const float*)d_in[8];
    const float* att1 = (const float*)d_in[9];
    const float* bias1 = (const float*)d_in[10];
    const float* Wl2 = (const float*)d_in[11];
    const float* bl2 = (const float*)d_in[12];
    const float* Wr2 = (const float*)d_in[13];
    const float* br2 = (const float*)d_in[14];
    const float* att2 = (const float*)d_in[15];
    const float* bias2 = (const float*)d_in[16];
    const float* linW = (const float*)d_in[17];
    const float* linb = (const float*)d_in[18];
    float* outp = (float*)d_out;

    int N = in_sizes[0] / XCOLS;   // 100000
    int E = in_sizes[1] / 2;       // 1600000
    int NB = (N + BSZ - 1) >> BSH; // 782

    char* p = (char*)d_ws;
    auto alloc = [&](size_t bytes) {
        void* r = (void*)p;
        p += (bytes + 255) & ~(size_t)255;
        return r;
    };
    float* h0 = (float*)alloc((size_t)N * EMB * 4);
    float* bufA = (float*)alloc((size_t)N * EMB * 4);
    float* bufB = (float*)alloc((size_t)N * EMB * 4);
    int* bcount = (int*)alloc(MAXNB * 4);
    int* boffs = (int*)alloc((MAXNB + 1) * 4);
    int* bcursor = (int*)alloc(MAXNB * 4);
    int* offs = (int*)alloc((size_t)(N + 1) * 4);
    int* epart = (int*)alloc((size_t)E * 4);
    int* ssrc = (int*)alloc((size_t)(E + 64) * 4);   // +pad for pipelined over-read

    int ngrp = (N + 3) / 4;

    // CSR build (2-level radix partition)
    zero_kernel<<<(NB + 255) / 256, 256, 0, stream>>>(bcount, NB);
    bincount_kernel<<<512, 256, 0, stream>>>(ei, bcount, offs, E, NB, N);
    bscan_kernel<<<1, 1024, 0, stream>>>(bcount, boffs, bcursor, NB);
    partition_kernel<<<(E + PCHUNK - 1) / PCHUNK, 256, 0, stream>>>(ei, bcursor, epart, E, NB);
    finalize_kernel<<<NB, 256, 0, stream>>>(epart, boffs, offs, ssrc, N);

    // node pipeline
    embed_kernel<<<ngrp, 256, 0, stream>>>(x, birth_tab, gender_tab, symp_tab, h0, N);
    gemm_dual_kernel<<<768, 256, 0, stream>>>(h0, Wl1, bl1, Wr1, br1, bufA, bufB, N);
    gat_kernel<1><<<ngrp, 256, 0, stream>>>(bufA, bufB, offs, ssrc, att1, bias1,
                                            nullptr, nullptr, h0, N);
    gemm_dual_kernel<<<768, 256, 0, stream>>>(h0, Wl2, bl2, Wr2, br2, bufA, bufB, N);
    gat_kernel<2><<<ngrp, 256, 0, stream>>>(bufA, bufB, offs, ssrc, att2, bias2,
                                            linW, linb, outp, N);
}